// Round 10
// baseline (254.224 us; speedup 1.0000x reference)
//
#include <hip/hip_runtime.h>

// Problem constants
#define Bc 4
#define Tc 2048
#define Dc 1024
#define Hc 16
#define HDc 64
#define VDc 64
#define MTOT (Bc * Tc)      // 8192 rows of x / out
#define NQKV 3072           // Q|K|V stacked output columns

typedef __attribute__((ext_vector_type(8))) short short8;   // 8 x bf16 (4 VGPRs)
typedef __attribute__((ext_vector_type(4))) short short4_;
typedef __attribute__((ext_vector_type(4))) float float4_;
typedef __attribute__((ext_vector_type(4))) unsigned uint4_;

#define QSCALE 0.18033688011112042f   // (1/sqrt(64)) * log2(e), folded into Q

// fp32 -> bf16 (RNE), bit-level
static __device__ __forceinline__ short f2bf(float f) {
  unsigned u = __builtin_bit_cast(unsigned, f);
  u += 0x7fffu + ((u >> 16) & 1u);
  return (short)(u >> 16);
}
// two fp32 -> bf16x2 dword via hardware packed convert (1 VALU op).
// v_cvt_pk_bf16_f32 d,s0,s1: LOW16 = bf16(s0), HIGH16 = bf16(s1).
static __device__ __forceinline__ unsigned cvtpk(float lo, float hi) {
  unsigned r;
  asm("v_cvt_pk_bf16_f32 %0, %1, %2" : "=v"(r) : "v"(lo), "v"(hi));
  return r;
}

// async global->LDS, 16B per lane; l must be wave-uniform (lane*16 implicit)
static __device__ __forceinline__ void gload16(const void* g, void* l) {
  __builtin_amdgcn_global_load_lds(
      (__attribute__((address_space(1))) void*)(unsigned long long)g,
      (__attribute__((address_space(3))) void*)l, 16, 0, 0);
}

// ---------------- fused prep: cvt_x | build_wqkv | build_wo ----------------
// One dispatch, block-uniform branch on flattened blockIdx:
//   [0, 8192)        cvt_x       (8M bf16 elements, 1024/block)
//   [8192, 8384)     build_wqkv  (48 x 4 tile grid)
//   [8384, 8640)     build_wo    (16 x 16 tile grid)
__global__ __launch_bounds__(256) void prep_kernel(
    const float* __restrict__ x, short* __restrict__ xb,
    const float* __restrict__ Wq, const float* __restrict__ Wk,
    const float* __restrict__ Wv, const float* __restrict__ bq,
    const float* __restrict__ bk, const float* __restrict__ bv,
    short* __restrict__ wt, float* __restrict__ bias,
    const float* __restrict__ Wo, short* __restrict__ wot) {
  __shared__ __align__(16) short Lt[64][72];
  const int tid = threadIdx.x;
  const int bid = blockIdx.x;

  if (bid < 8192) {                       // ---- cvt_x ----
    int i = bid * 256 + tid;
    float4_ v = reinterpret_cast<const float4_*>(x)[i];
    short4_ o;
    o[0] = f2bf(v[0]); o[1] = f2bf(v[1]); o[2] = f2bf(v[2]); o[3] = f2bf(v[3]);
    reinterpret_cast<short4_*>(xb)[i] = o;
    return;
  }

  if (bid < 8384) {                       // ---- build_wqkv ----
    const int idx = bid - 8192;
    const int wx = idx % 48, wy = idx / 48;
    const int mat = wx >> 4, h = wx & 15;
    const float* W  = (mat == 0) ? Wq : (mat == 1) ? Wk : Wv;
    const float* bs = (mat == 0) ? bq : (mat == 1) ? bk : bv;
    const int base_n = (mat << 10) + (h << 6);
    if (wy == 0 && tid < 64) bias[base_n + tid] = bs[h * 64 + tid];
    for (int dc = 0; dc < 4; dc++) {
      const int d0 = wy * 256 + dc * 64;
#pragma unroll
      for (int rep = 0; rep < 16; rep++) {
        int dl = rep * 4 + (tid >> 6);
        int hd = tid & 63;
        Lt[hd][dl] = f2bf(W[(size_t)(h * 1024 + d0 + dl) * 64 + hd]);
      }
      __syncthreads();
      int hd = tid >> 2, c = tid & 3;
      short8 v0 = *(const short8*)&Lt[hd][c * 16];
      short8 v1 = *(const short8*)&Lt[hd][c * 16 + 8];
      *(short8*)&wt[(size_t)(base_n + hd) * 1024 + d0 + c * 16] = v0;
      *(short8*)&wt[(size_t)(base_n + hd) * 1024 + d0 + c * 16 + 8] = v1;
      __syncthreads();
    }
    return;
  }

  {                                       // ---- build_wo ----
    const int idx = bid - 8384;
    const int n0 = (idx & 15) * 64, k0 = (idx >> 4) * 64;
#pragma unroll
    for (int rep = 0; rep < 16; rep++) {
      int kl = rep * 4 + (tid >> 6);
      int nl = tid & 63;
      Lt[nl][kl] = f2bf(Wo[(size_t)(k0 + kl) * 1024 + n0 + nl]);
    }
    __syncthreads();
    int nl = tid >> 2, c = tid & 3;
    short8 v0 = *(const short8*)&Lt[nl][c * 16];
    short8 v1 = *(const short8*)&Lt[nl][c * 16 + 8];
    *(short8*)&wot[(size_t)(n0 + nl) * 1024 + k0 + c * 16] = v0;
    *(short8*)&wot[(size_t)(n0 + nl) * 1024 + k0 + c * 16 + 8] = v1;
  }
}

// ---------------- double-buffered LDS-staged GEMM K-loop ----------------
#define GEMM_KLOOP(SHSZ)                                                       \
  __shared__ __align__(16) short Sh[SHSZ];                                     \
  const int tid = threadIdx.x;                                                 \
  const int wave = tid >> 6, lane = tid & 63;                                  \
  const int lm = lane & 15, quad = lane >> 4;                                  \
  const int wm = (wave & 1) * 64, wn = (wave >> 1) * 64;                       \
  const int srow = tid >> 2, pchunk = tid & 3;                                 \
  const int swr = (srow ^ (srow >> 2)) & 3;                                    \
  const int pq = quad ^ ((lm ^ (lm >> 2)) & 3);                                \
  const short* Ag = A + (size_t)(m0 + srow) * 1024 + (pchunk ^ swr) * 8;       \
  const short* Bg = Bt + (size_t)(n0 + srow) * 1024 + (pchunk ^ swr) * 8;      \
  float4_ acc[4][4] = {};                                                      \
  gload16(Ag, &Sh[wave * 512]);                                                \
  gload16(Ag + 64 * 1024, &Sh[2048 + wave * 512]);                             \
  gload16(Bg, &Sh[4096 + wave * 512]);                                         \
  gload16(Bg + 64 * 1024, &Sh[6144 + wave * 512]);                             \
  for (int k0 = 0; k0 < 1024; k0 += 32) {                                      \
    const int cb = (k0 >> 5) & 1;                                              \
    __syncthreads();                                                           \
    if (k0 + 32 < 1024) {                                                      \
      short* d = &Sh[(1 - cb) * 8192];                                         \
      gload16(Ag + k0 + 32, d + wave * 512);                                   \
      gload16(Ag + 64 * 1024 + k0 + 32, d + 2048 + wave * 512);                \
      gload16(Bg + k0 + 32, d + 4096 + wave * 512);                            \
      gload16(Bg + 64 * 1024 + k0 + 32, d + 6144 + wave * 512);                \
    }                                                                          \
    const short* Ab = &Sh[cb * 8192];                                          \
    const short* Bb = &Sh[cb * 8192 + 4096];                                   \
    short8 af[4], bf[4];                                                       \
    _Pragma("unroll") for (int i = 0; i < 4; i++) {                            \
      af[i] = *(const short8*)&Ab[(wm + i * 16 + lm) * 32 + pq * 8];           \
      bf[i] = *(const short8*)&Bb[(wn + i * 16 + lm) * 32 + pq * 8];           \
    }                                                                          \
    _Pragma("unroll") for (int i = 0; i < 4; i++)                              \
      _Pragma("unroll") for (int j = 0; j < 4; j++)                            \
        acc[i][j] = __builtin_amdgcn_mfma_f32_16x16x32_bf16(af[i], bf[j],      \
                                                            acc[i][j], 0, 0, 0); \
  }

// QKV projection: A = xb [8192][1024], Bt = wqkv [3072][1024].
// XCD-aware bijective swizzle: 1536 blocks = 8 XCDs x 192; each XCD gets a
// contiguous run of tiles (3 n-panels x 64 m) -> B-panel stays in one L2.
__global__ __launch_bounds__(256) void gemm_qkv_kernel(
    const short* __restrict__ A, const short* __restrict__ Bt,
    const float* __restrict__ bias,
    short* __restrict__ Qb, short* __restrict__ Kb, short* __restrict__ Vt) {
  const int lb = blockIdx.x + 64 * blockIdx.y;
  const int swz = (lb & 7) * 192 + (lb >> 3);      // bijective: 1536 = 8*192
  const int m0 = (swz & 63) * 128, n0 = (swz >> 6) * 128;
  GEMM_KLOOP(18432)
  __syncthreads();                       // all waves done reading Sh
  short* epi = &Sh[wave * 4608];         // 64 x 72 shorts per wave
  const int mat = n0 >> 10;
  const int hh = ((n0 + wn) >> 6) & 15;
  const int b = m0 >> 11;
  const int bh = b * Hc + hh;
  const int t0 = (m0 & (Tc - 1)) + wm;
  if (mat < 2) {                         // Q/K: epi[t][hd]
    const float sc = (mat == 0) ? QSCALE : 1.0f;
#pragma unroll
    for (int j = 0; j < 4; j++) {
      float bvs = bias[n0 + wn + j * 16 + lm] * sc;
#pragma unroll
      for (int i = 0; i < 4; i++)
#pragma unroll
        for (int r = 0; r < 4; r++)
          epi[(i * 16 + quad * 4 + r) * 72 + j * 16 + lm] = f2bf(acc[i][j][r] * sc + bvs);
    }
    __asm__ volatile("s_waitcnt lgkmcnt(0)" ::: "memory");
    short* dst = (mat == 0) ? Qb : Kb;
#pragma unroll
    for (int p = 0; p < 8; p++) {
      int lrow = p * 8 + (lane >> 3);
      short8 v = *(const short8*)&epi[lrow * 72 + (lane & 7) * 8];
      *(short8*)&dst[((size_t)bh * Tc + t0 + lrow) * HDc + (lane & 7) * 8] = v;
    }
  } else {                               // V: epi[hd][t] (transposed, b64 packs)
#pragma unroll
    for (int j = 0; j < 4; j++) {
      float bv = bias[n0 + wn + j * 16 + lm];
#pragma unroll
      for (int i = 0; i < 4; i++) {
        short4_ pk;
#pragma unroll
        for (int r = 0; r < 4; r++) pk[r] = f2bf(acc[i][j][r] + bv);
        *(short4_*)&epi[(j * 16 + lm) * 72 + i * 16 + quad * 4] = pk;
      }
    }
    __asm__ volatile("s_waitcnt lgkmcnt(0)" ::: "memory");
#pragma unroll
    for (int p = 0; p < 8; p++) {
      int hdrow = p * 8 + (lane >> 3);
      short8 v = *(const short8*)&epi[hdrow * 72 + (lane & 7) * 8];
      *(short8*)&Vt[((size_t)bh * VDc + hdrow) * Tc + t0 + (lane & 7) * 8] = v;
    }
  }
}

// Output projection: A = AO [8192][1024], Bt = wot [1024][1024], fp32 out.
// XCD-aware bijective swizzle: 512 blocks = 8 XCDs x 64 (one n-panel each).
__global__ __launch_bounds__(256) void gemm_out_kernel(
    const short* __restrict__ A, const short* __restrict__ Bt,
    const float* __restrict__ bo, float* __restrict__ out) {
  const int lb = blockIdx.x + 64 * blockIdx.y;
  const int swz = (lb & 7) * 64 + (lb >> 3);       // bijective: 512 = 8*64
  const int m0 = (swz & 63) * 128, n0 = (swz >> 6) * 128;
  GEMM_KLOOP(16384)
#pragma unroll
  for (int j = 0; j < 4; j++) {
    int n = n0 + wn + j * 16 + lm;
    float bv = bo[n];
#pragma unroll
    for (int i = 0; i < 4; i++) {
#pragma unroll
      for (int r = 0; r < 4; r++) {
        int m = m0 + wm + i * 16 + quad * 4 + r;
        out[(size_t)m * Dc + n] = acc[i][j][r] + bv;
      }
    }
  }
}

// ---------------- flash attention (causal), transposed scores ----------------
// Pair-block version of the R7 skeleton: ONE 512-thread block handles the
// complementary qblk pair {7-p, p} for one (b,h). Waves 0-3 own qblk 7-p
// (rows (7-p)*256 + w*64), waves 4-7 own qblk p. Since qblk p's key range
// [0, 256p+256) is a PREFIX of qblk 7-p's [0, 256(7-p)+256), ONE shared K/V
// staging stream serves both: nt = 4*(7-p)+4 tiles, small-qblk waves skip
// the suffix via the same wave-uniform continue. Per-wave compute body,
// LDS tile layout, chunk-XOR swizzle, and double-buffer bases are IDENTICAL
// to R7 (Kt=&Sh[cur*4096], Vtl=&Sh[8192+cur*4096]); with 512 threads,
// srow=tid>>3 spans all 64 rows so each thread stages 1 K + 1 V chunk/tile.
// Grid (64 bh, 4 p): same-bh blocks land on one XCD (ids bh+64p -> XCD bh%8).
// s_setprio(1) around MFMA clusters (T5): staggers co-SIMD waves so one
// wave's MFMA overlaps the other's exp2/VALU phase (+4-7% attn, m191).
__global__ __launch_bounds__(512, 2) void attn_kernel(
    const short* __restrict__ Qb, const short* __restrict__ Kb,
    const short* __restrict__ Vt, short* __restrict__ AO) {
  __shared__ __align__(16) short Sh[32768];
  const int tid = threadIdx.x;
  const int wave = tid >> 6, lane = tid & 63;
  const int lm = lane & 15, quad = lane >> 4;
  const int bh = blockIdx.x;
  const int p = blockIdx.y;                   // pair index 0..3
  const int qblk = (wave < 4) ? (7 - p) : p;
  const int q0 = qblk * 256 + (wave & 3) * 64;
  const int nt = 4 * (7 - p) + 4;             // loop bound = large member's

  const short* Qp = Qb + (size_t)bh * Tc * HDc;
  const short* Kp = Kb + (size_t)bh * Tc * HDc;
  const short* Vp = Vt + (size_t)bh * VDc * Tc;

  const int srow = tid >> 3;                 // 0..63 (512 threads)
  const int chlog = (tid & 7) ^ (srow & 7);
  const int sw = lm & 7;

  short8 qf[4][2];
#pragma unroll
  for (int g = 0; g < 4; g++)
#pragma unroll
    for (int h = 0; h < 2; h++)
      qf[g][h] = *(const short8*)&Qp[(q0 + g * 16 + lm) * HDc + h * 32 + quad * 8];

  float4_ o[4][4] = {};        // Oᵀ[vd=16mf2+4quad+r][qrow=16g+lm]
  float lsum[4] = {};
  unsigned pk[4][4][2];        // pk[mf][g]: keys {16mf+4q+0..3} as bf16x2 pairs

  // prologue: tile 0 (each thread: 1 K chunk + 1 V chunk)
  gload16(Kp + (size_t)srow * HDc + chlog * 8, &Sh[wave * 512]);
  gload16(Vp + (size_t)srow * Tc + chlog * 8, &Sh[8192 + wave * 512]);

  for (int it = 0; it < nt; ++it) {
    const int kt = it << 6;
    const int cur = it & 1;
    __syncthreads();                    // tile `it` staged
    if (it + 1 < nt) {
      const int ktn = kt + 64;
      const int nb = (1 - cur) * 4096;
      gload16(Kp + (size_t)(ktn + srow) * HDc + chlog * 8, &Sh[nb + wave * 512]);
      gload16(Vp + (size_t)srow * Tc + ktn + chlog * 8, &Sh[8192 + nb + wave * 512]);
    }
    if (kt > q0 + 63) continue;         // fully-masked tile (wave-uniform)
    const short* Kt = &Sh[cur * 4096];
    const short* Vtl = &Sh[8192 + cur * 4096];
    const bool diag = (kt + 63 > q0);

#pragma unroll
    for (int mf = 0; mf < 4; ++mf) {
      int row = mf * 16 + lm;
      short8 k0 = *(const short8*)&Kt[row * 64 + (quad ^ sw) * 8];
      short8 k1 = *(const short8*)&Kt[row * 64 + ((4 + quad) ^ sw) * 8];
      float4_ st[4];
      __builtin_amdgcn_s_setprio(1);
#pragma unroll
      for (int g = 0; g < 4; ++g) {
        float4_ s = {};
        s = __builtin_amdgcn_mfma_f32_16x16x32_bf16(k0, qf[g][0], s, 0, 0, 0);
        s = __builtin_amdgcn_mfma_f32_16x16x32_bf16(k1, qf[g][1], s, 0, 0, 0);
        st[g] = s;
      }
      __builtin_amdgcn_s_setprio(0);
      if (diag) {
#pragma unroll
        for (int g = 0; g < 4; ++g) {
          int qrow = q0 + g * 16 + lm;
#pragma unroll
          for (int r = 0; r < 4; ++r)
            if (kt + mf * 16 + quad * 4 + r > qrow) st[g][r] = -1e30f;
        }
      }
#pragma unroll
      for (int g = 0; g < 4; ++g) {
        float p0 = __builtin_amdgcn_exp2f(st[g][0]);
        float p1 = __builtin_amdgcn_exp2f(st[g][1]);
        float p2 = __builtin_amdgcn_exp2f(st[g][2]);
        float p3 = __builtin_amdgcn_exp2f(st[g][3]);
        lsum[g] += (p0 + p1) + (p2 + p3);
        pk[mf][g][0] = cvtpk(p0, p1);   // p0 low | p1 high
        pk[mf][g][1] = cvtpk(p2, p3);
      }
    }

#pragma unroll
    for (int h = 0; h < 2; ++h) {
      short8 bfr[4];
#pragma unroll
      for (int g = 0; g < 4; ++g) {
        uint4_ bu = {pk[2 * h][g][0], pk[2 * h][g][1], pk[2 * h + 1][g][0], pk[2 * h + 1][g][1]};
        bfr[g] = __builtin_bit_cast(short8, bu);
      }
#pragma unroll
      for (int mf2 = 0; mf2 < 4; ++mf2) {
        int row = mf2 * 16 + lm;
        // permuted-key V A-frag: keys {32h+4q+0..3} and {32h+16+4q+0..3}
        short4_ va = *(const short4_*)&Vtl[row * 64 + ((4 * h + (quad >> 1)) ^ sw) * 8 + (quad & 1) * 4];
        short4_ vb = *(const short4_*)&Vtl[row * 64 + ((4 * h + 2 + (quad >> 1)) ^ sw) * 8 + (quad & 1) * 4];
        short8 af = __builtin_shufflevector(va, vb, 0, 1, 2, 3, 4, 5, 6, 7);
        __builtin_amdgcn_s_setprio(1);
#pragma unroll
        for (int g = 0; g < 4; ++g)
          o[mf2][g] = __builtin_amdgcn_mfma_f32_16x16x32_bf16(af, bfr[g], o[mf2][g], 0, 0, 0);
        __builtin_amdgcn_s_setprio(0);
      }
    }
  }

  // denominator: cross-quad reduce of per-lane partials (once)
  float inv[4];
#pragma unroll
  for (int g = 0; g < 4; ++g) {
    float s = lsum[g];
    s += __shfl_xor(s, 16);
    s += __shfl_xor(s, 32);
    inv[g] = 1.0f / s;
  }

  // epilogue: normalize, swizzled-LDS transpose (reuse staging), coalesced store
  __syncthreads();                       // all waves done with Ks/Vs
  const int b = bh >> 4, h = bh & 15;
  short* epi = &Sh[wave * 4096];         // 64 rows x 64 vd per wave (8 waves)
#pragma unroll
  for (int g = 0; g < 4; ++g) {
#pragma unroll
    for (int mf2 = 0; mf2 < 4; ++mf2) {
      short4_ pkv;
      pkv[0] = f2bf(o[mf2][g][0] * inv[g]); pkv[1] = f2bf(o[mf2][g][1] * inv[g]);
      pkv[2] = f2bf(o[mf2][g][2] * inv[g]); pkv[3] = f2bf(o[mf2][g][3] * inv[g]);
      *(short4_*)&epi[(g * 16 + lm) * 64 + ((2 * mf2 + (quad >> 1)) ^ sw) * 8 + (quad & 1) * 4] = pkv;
    }
  }
  __asm__ volatile("s_waitcnt lgkmcnt(0)" ::: "memory");
#pragma unroll
  for (int pp = 0; pp < 8; ++pp) {
    int lr = pp * 8 + (lane >> 3);
    short8 vv = *(const short8*)&epi[lr * 64 + ((lane & 7) ^ (lr & 7)) * 8];
    *(short8*)&AO[((size_t)(b * Tc + q0 + lr)) * 1024 + h * 64 + (lane & 7) * 8] = vv;
  }
}

// ---------------- launch ----------------
extern "C" void kernel_launch(void* const* d_in, const int* in_sizes, int n_in,
                              void* d_out, int out_size, void* d_ws, size_t ws_size,
                              hipStream_t stream) {
  const float* x  = (const float*)d_in[0];
  const float* Wq = (const float*)d_in[1];
  const float* bq = (const float*)d_in[2];
  const float* Wk = (const float*)d_in[3];
  const float* bk = (const float*)d_in[4];
  const float* Wv = (const float*)d_in[5];
  const float* bv = (const float*)d_in[6];
  const float* Wo = (const float*)d_in[7];
  const float* bo = (const float*)d_in[8];
  float* out = (float*)d_out;

  char* ws = (char*)d_ws;
  size_t off = 0;
  short* xb   = (short*)(ws + off); off += (size_t)MTOT * Dc * 2;
  short* wqkv = (short*)(ws + off); off += (size_t)NQKV * Dc * 2;
  float* bqkv = (float*)(ws + off); off += ((size_t)NQKV * 4 + 255) & ~255ull;
  short* Qb   = (short*)(ws + off); off += (size_t)Bc * Hc * Tc * HDc * 2;
  short* Kb   = (short*)(ws + off); off += (size_t)Bc * Hc * Tc * HDc * 2;
  short* Vt   = (short*)(ws + off); off += (size_t)Bc * Hc * VDc * Tc * 2;
  short* AO   = (short*)(ws + off); off += (size_t)MTOT * 1024 * 2;
  short* wot  = (short*)(ws + off); off += (size_t)Dc * Dc * 2;

  prep_kernel<<<8640, 256, 0, stream>>>(x, xb, Wq, Wk, Wv, bq, bk, bv,
                                        wqkv, bqkv, Wo, wot);
  gemm_qkv_kernel<<<dim3(MTOT / 128, NQKV / 128), 256, 0, stream>>>(xb, wqkv, bqkv, Qb, Kb, Vt);
  attn_kernel<<<dim3(64, 4), 512, 0, stream>>>(Qb, Kb, Vt, AO);
  gemm_out_kernel<<<dim3(MTOT / 128, Dc / 128), 256, 0, stream>>>(AO, wot, bo, out);
}

// Round 11
// 233.692 us; speedup vs baseline: 1.0879x; 1.0879x over previous
//
#include <hip/hip_runtime.h>

// Problem constants
#define Bc 4
#define Tc 2048
#define Dc 1024
#define Hc 16
#define HDc 64
#define VDc 64
#define MTOT (Bc * Tc)      // 8192 rows of x / out
#define NQKV 3072           // Q|K|V stacked output columns

typedef __attribute__((ext_vector_type(8))) short short8;   // 8 x bf16 (4 VGPRs)
typedef __attribute__((ext_vector_type(4))) short short4_;
typedef __attribute__((ext_vector_type(4))) float float4_;
typedef __attribute__((ext_vector_type(4))) unsigned uint4_;

#define QSCALE 0.18033688011112042f   // (1/sqrt(64)) * log2(e), folded into Q

// fp32 -> bf16 (RNE), bit-level
static __device__ __forceinline__ short f2bf(float f) {
  unsigned u = __builtin_bit_cast(unsigned, f);
  u += 0x7fffu + ((u >> 16) & 1u);
  return (short)(u >> 16);
}
// two fp32 -> bf16x2 dword via hardware packed convert (1 VALU op).
// v_cvt_pk_bf16_f32 d,s0,s1: LOW16 = bf16(s0), HIGH16 = bf16(s1).
static __device__ __forceinline__ unsigned cvtpk(float lo, float hi) {
  unsigned r;
  asm("v_cvt_pk_bf16_f32 %0, %1, %2" : "=v"(r) : "v"(lo), "v"(hi));
  return r;
}

// async global->LDS, 16B per lane; l must be wave-uniform (lane*16 implicit)
static __device__ __forceinline__ void gload16(const void* g, void* l) {
  __builtin_amdgcn_global_load_lds(
      (__attribute__((address_space(1))) void*)(unsigned long long)g,
      (__attribute__((address_space(3))) void*)l, 16, 0, 0);
}

// ---------------- fused prep: build_wqkv | build_wo | cvt_x ----------------
// One dispatch. Heavy LDS-transpose blocks FIRST (longest-job-first: they
// have serial __syncthreads phases and would otherwise form the tail):
//   [0, 192)         build_wqkv  (48 x 4 tile grid)
//   [192, 448)       build_wo    (16 x 16 tile grid)
//   [448, 8640)      cvt_x       (8M bf16 elements, 1024/block)
__global__ __launch_bounds__(256) void prep_kernel(
    const float* __restrict__ x, short* __restrict__ xb,
    const float* __restrict__ Wq, const float* __restrict__ Wk,
    const float* __restrict__ Wv, const float* __restrict__ bq,
    const float* __restrict__ bk, const float* __restrict__ bv,
    short* __restrict__ wt, float* __restrict__ bias,
    const float* __restrict__ Wo, short* __restrict__ wot) {
  __shared__ __align__(16) short Lt[64][72];
  const int tid = threadIdx.x;
  const int bid = blockIdx.x;

  if (bid >= 448) {                       // ---- cvt_x ----
    int i = (bid - 448) * 256 + tid;
    float4_ v = reinterpret_cast<const float4_*>(x)[i];
    short4_ o;
    o[0] = f2bf(v[0]); o[1] = f2bf(v[1]); o[2] = f2bf(v[2]); o[3] = f2bf(v[3]);
    reinterpret_cast<short4_*>(xb)[i] = o;
    return;
  }

  if (bid < 192) {                        // ---- build_wqkv ----
    const int idx = bid;
    const int wx = idx % 48, wy = idx / 48;
    const int mat = wx >> 4, h = wx & 15;
    const float* W  = (mat == 0) ? Wq : (mat == 1) ? Wk : Wv;
    const float* bs = (mat == 0) ? bq : (mat == 1) ? bk : bv;
    const int base_n = (mat << 10) + (h << 6);
    if (wy == 0 && tid < 64) bias[base_n + tid] = bs[h * 64 + tid];
    for (int dc = 0; dc < 4; dc++) {
      const int d0 = wy * 256 + dc * 64;
#pragma unroll
      for (int rep = 0; rep < 16; rep++) {
        int dl = rep * 4 + (tid >> 6);
        int hd = tid & 63;
        Lt[hd][dl] = f2bf(W[(size_t)(h * 1024 + d0 + dl) * 64 + hd]);
      }
      __syncthreads();
      int hd = tid >> 2, c = tid & 3;
      short8 v0 = *(const short8*)&Lt[hd][c * 16];
      short8 v1 = *(const short8*)&Lt[hd][c * 16 + 8];
      *(short8*)&wt[(size_t)(base_n + hd) * 1024 + d0 + c * 16] = v0;
      *(short8*)&wt[(size_t)(base_n + hd) * 1024 + d0 + c * 16 + 8] = v1;
      __syncthreads();
    }
    return;
  }

  {                                       // ---- build_wo ----
    const int idx = bid - 192;
    const int n0 = (idx & 15) * 64, k0 = (idx >> 4) * 64;
#pragma unroll
    for (int rep = 0; rep < 16; rep++) {
      int kl = rep * 4 + (tid >> 6);
      int nl = tid & 63;
      Lt[nl][kl] = f2bf(Wo[(size_t)(k0 + kl) * 1024 + n0 + nl]);
    }
    __syncthreads();
    int nl = tid >> 2, c = tid & 3;
    short8 v0 = *(const short8*)&Lt[nl][c * 16];
    short8 v1 = *(const short8*)&Lt[nl][c * 16 + 8];
    *(short8*)&wot[(size_t)(n0 + nl) * 1024 + k0 + c * 16] = v0;
    *(short8*)&wot[(size_t)(n0 + nl) * 1024 + k0 + c * 16 + 8] = v1;
  }
}

// ---------------- double-buffered LDS-staged GEMM K-loop ----------------
#define GEMM_KLOOP(SHSZ)                                                       \
  __shared__ __align__(16) short Sh[SHSZ];                                     \
  const int tid = threadIdx.x;                                                 \
  const int wave = tid >> 6, lane = tid & 63;                                  \
  const int lm = lane & 15, quad = lane >> 4;                                  \
  const int wm = (wave & 1) * 64, wn = (wave >> 1) * 64;                       \
  const int srow = tid >> 2, pchunk = tid & 3;                                 \
  const int swr = (srow ^ (srow >> 2)) & 3;                                    \
  const int pq = quad ^ ((lm ^ (lm >> 2)) & 3);                                \
  const short* Ag = A + (size_t)(m0 + srow) * 1024 + (pchunk ^ swr) * 8;       \
  const short* Bg = Bt + (size_t)(n0 + srow) * 1024 + (pchunk ^ swr) * 8;      \
  float4_ acc[4][4] = {};                                                      \
  gload16(Ag, &Sh[wave * 512]);                                                \
  gload16(Ag + 64 * 1024, &Sh[2048 + wave * 512]);                             \
  gload16(Bg, &Sh[4096 + wave * 512]);                                         \
  gload16(Bg + 64 * 1024, &Sh[6144 + wave * 512]);                             \
  for (int k0 = 0; k0 < 1024; k0 += 32) {                                      \
    const int cb = (k0 >> 5) & 1;                                              \
    __syncthreads();                                                           \
    if (k0 + 32 < 1024) {                                                      \
      short* d = &Sh[(1 - cb) * 8192];                                         \
      gload16(Ag + k0 + 32, d + wave * 512);                                   \
      gload16(Ag + 64 * 1024 + k0 + 32, d + 2048 + wave * 512);                \
      gload16(Bg + k0 + 32, d + 4096 + wave * 512);                            \
      gload16(Bg + 64 * 1024 + k0 + 32, d + 6144 + wave * 512);                \
    }                                                                          \
    const short* Ab = &Sh[cb * 8192];                                          \
    const short* Bb = &Sh[cb * 8192 + 4096];                                   \
    short8 af[4], bf[4];                                                       \
    _Pragma("unroll") for (int i = 0; i < 4; i++) {                            \
      af[i] = *(const short8*)&Ab[(wm + i * 16 + lm) * 32 + pq * 8];           \
      bf[i] = *(const short8*)&Bb[(wn + i * 16 + lm) * 32 + pq * 8];           \
    }                                                                          \
    _Pragma("unroll") for (int i = 0; i < 4; i++)                              \
      _Pragma("unroll") for (int j = 0; j < 4; j++)                            \
        acc[i][j] = __builtin_amdgcn_mfma_f32_16x16x32_bf16(af[i], bf[j],      \
                                                            acc[i][j], 0, 0, 0); \
  }

// QKV projection: A = xb [8192][1024], Bt = wqkv [3072][1024].
// Default block mapping is already XCD-optimal: grid (64 m, 24 n) with
// 64 % 8 == 0 gives XCD = m mod 8 -> each XCD keeps 8 A-panels (2 MB)
// L2-resident, reused across all 24 n-panels. Do NOT swizzle (R10: 4x FETCH).
__global__ __launch_bounds__(256) void gemm_qkv_kernel(
    const short* __restrict__ A, const short* __restrict__ Bt,
    const float* __restrict__ bias,
    short* __restrict__ Qb, short* __restrict__ Kb, short* __restrict__ Vt) {
  const int m0 = blockIdx.x * 128, n0 = blockIdx.y * 128;
  GEMM_KLOOP(18432)
  __syncthreads();                       // all waves done reading Sh
  short* epi = &Sh[wave * 4608];         // 64 x 72 shorts per wave
  const int mat = n0 >> 10;
  const int hh = ((n0 + wn) >> 6) & 15;
  const int b = m0 >> 11;
  const int bh = b * Hc + hh;
  const int t0 = (m0 & (Tc - 1)) + wm;
  if (mat < 2) {                         // Q/K: epi[t][hd]
    const float sc = (mat == 0) ? QSCALE : 1.0f;
#pragma unroll
    for (int j = 0; j < 4; j++) {
      float bvs = bias[n0 + wn + j * 16 + lm] * sc;
#pragma unroll
      for (int i = 0; i < 4; i++)
#pragma unroll
        for (int r = 0; r < 4; r++)
          epi[(i * 16 + quad * 4 + r) * 72 + j * 16 + lm] = f2bf(acc[i][j][r] * sc + bvs);
    }
    __asm__ volatile("s_waitcnt lgkmcnt(0)" ::: "memory");
    short* dst = (mat == 0) ? Qb : Kb;
#pragma unroll
    for (int p = 0; p < 8; p++) {
      int lrow = p * 8 + (lane >> 3);
      short8 v = *(const short8*)&epi[lrow * 72 + (lane & 7) * 8];
      *(short8*)&dst[((size_t)bh * Tc + t0 + lrow) * HDc + (lane & 7) * 8] = v;
    }
  } else {                               // V: epi[hd][t] (transposed, b64 packs)
#pragma unroll
    for (int j = 0; j < 4; j++) {
      float bv = bias[n0 + wn + j * 16 + lm];
#pragma unroll
      for (int i = 0; i < 4; i++) {
        short4_ pk;
#pragma unroll
        for (int r = 0; r < 4; r++) pk[r] = f2bf(acc[i][j][r] + bv);
        *(short4_*)&epi[(j * 16 + lm) * 72 + i * 16 + quad * 4] = pk;
      }
    }
    __asm__ volatile("s_waitcnt lgkmcnt(0)" ::: "memory");
#pragma unroll
    for (int p = 0; p < 8; p++) {
      int hdrow = p * 8 + (lane >> 3);
      short8 v = *(const short8*)&epi[hdrow * 72 + (lane & 7) * 8];
      *(short8*)&Vt[((size_t)bh * VDc + hdrow) * Tc + t0 + (lane & 7) * 8] = v;
    }
  }
}

// Output projection: A = AO [8192][1024], Bt = wot [1024][1024], fp32 out.
__global__ __launch_bounds__(256) void gemm_out_kernel(
    const short* __restrict__ A, const short* __restrict__ Bt,
    const float* __restrict__ bo, float* __restrict__ out) {
  const int m0 = blockIdx.x * 128, n0 = blockIdx.y * 128;
  GEMM_KLOOP(16384)
#pragma unroll
  for (int j = 0; j < 4; j++) {
    int n = n0 + wn + j * 16 + lm;
    float bv = bo[n];
#pragma unroll
    for (int i = 0; i < 4; i++) {
#pragma unroll
      for (int r = 0; r < 4; r++) {
        int m = m0 + wm + i * 16 + quad * 4 + r;
        out[(size_t)m * Dc + n] = acc[i][j][r] + bv;
      }
    }
  }
}

// ---------------- flash attention (causal), transposed scores ----------------
// Pair-block version of the R7 skeleton: ONE 512-thread block handles the
// complementary qblk pair {7-p, p} for one (b,h). Waves 0-3 own qblk 7-p
// (rows (7-p)*256 + w*64), waves 4-7 own qblk p. Since qblk p's key range
// [0, 256p+256) is a PREFIX of qblk 7-p's [0, 256(7-p)+256), ONE shared K/V
// staging stream serves both: nt = 4*(7-p)+4 tiles, small-qblk waves skip
// the suffix via the same wave-uniform continue. Per-wave compute body,
// LDS tile layout, chunk-XOR swizzle, and double-buffer bases are IDENTICAL
// to R7 (Kt=&Sh[cur*4096], Vtl=&Sh[8192+cur*4096]); with 512 threads,
// srow=tid>>3 spans all 64 rows so each thread stages 1 K + 1 V chunk/tile.
// Grid (64 bh, 4 p): same-bh blocks land on one XCD (ids bh+64p -> XCD bh%8).
// (setprio on MFMA clusters: tested R10, ~0 on this lockstep structure.)
__global__ __launch_bounds__(512, 2) void attn_kernel(
    const short* __restrict__ Qb, const short* __restrict__ Kb,
    const short* __restrict__ Vt, short* __restrict__ AO) {
  __shared__ __align__(16) short Sh[32768];
  const int tid = threadIdx.x;
  const int wave = tid >> 6, lane = tid & 63;
  const int lm = lane & 15, quad = lane >> 4;
  const int bh = blockIdx.x;
  const int p = blockIdx.y;                   // pair index 0..3
  const int qblk = (wave < 4) ? (7 - p) : p;
  const int q0 = qblk * 256 + (wave & 3) * 64;
  const int nt = 4 * (7 - p) + 4;             // loop bound = large member's

  const short* Qp = Qb + (size_t)bh * Tc * HDc;
  const short* Kp = Kb + (size_t)bh * Tc * HDc;
  const short* Vp = Vt + (size_t)bh * VDc * Tc;

  const int srow = tid >> 3;                 // 0..63 (512 threads)
  const int chlog = (tid & 7) ^ (srow & 7);
  const int sw = lm & 7;

  short8 qf[4][2];
#pragma unroll
  for (int g = 0; g < 4; g++)
#pragma unroll
    for (int h = 0; h < 2; h++)
      qf[g][h] = *(const short8*)&Qp[(q0 + g * 16 + lm) * HDc + h * 32 + quad * 8];

  float4_ o[4][4] = {};        // Oᵀ[vd=16mf2+4quad+r][qrow=16g+lm]
  float lsum[4] = {};
  unsigned pk[4][4][2];        // pk[mf][g]: keys {16mf+4q+0..3} as bf16x2 pairs

  // prologue: tile 0 (each thread: 1 K chunk + 1 V chunk)
  gload16(Kp + (size_t)srow * HDc + chlog * 8, &Sh[wave * 512]);
  gload16(Vp + (size_t)srow * Tc + chlog * 8, &Sh[8192 + wave * 512]);

  for (int it = 0; it < nt; ++it) {
    const int kt = it << 6;
    const int cur = it & 1;
    __syncthreads();                    // tile `it` staged
    if (it + 1 < nt) {
      const int ktn = kt + 64;
      const int nb = (1 - cur) * 4096;
      gload16(Kp + (size_t)(ktn + srow) * HDc + chlog * 8, &Sh[nb + wave * 512]);
      gload16(Vp + (size_t)srow * Tc + ktn + chlog * 8, &Sh[8192 + nb + wave * 512]);
    }
    if (kt > q0 + 63) continue;         // fully-masked tile (wave-uniform)
    const short* Kt = &Sh[cur * 4096];
    const short* Vtl = &Sh[8192 + cur * 4096];
    const bool diag = (kt + 63 > q0);

#pragma unroll
    for (int mf = 0; mf < 4; ++mf) {
      int row = mf * 16 + lm;
      short8 k0 = *(const short8*)&Kt[row * 64 + (quad ^ sw) * 8];
      short8 k1 = *(const short8*)&Kt[row * 64 + ((4 + quad) ^ sw) * 8];
      float4_ st[4];
#pragma unroll
      for (int g = 0; g < 4; ++g) {
        float4_ s = {};
        s = __builtin_amdgcn_mfma_f32_16x16x32_bf16(k0, qf[g][0], s, 0, 0, 0);
        s = __builtin_amdgcn_mfma_f32_16x16x32_bf16(k1, qf[g][1], s, 0, 0, 0);
        st[g] = s;
      }
      if (diag) {
#pragma unroll
        for (int g = 0; g < 4; ++g) {
          int qrow = q0 + g * 16 + lm;
#pragma unroll
          for (int r = 0; r < 4; ++r)
            if (kt + mf * 16 + quad * 4 + r > qrow) st[g][r] = -1e30f;
        }
      }
#pragma unroll
      for (int g = 0; g < 4; ++g) {
        float p0 = __builtin_amdgcn_exp2f(st[g][0]);
        float p1 = __builtin_amdgcn_exp2f(st[g][1]);
        float p2 = __builtin_amdgcn_exp2f(st[g][2]);
        float p3 = __builtin_amdgcn_exp2f(st[g][3]);
        lsum[g] += (p0 + p1) + (p2 + p3);
        pk[mf][g][0] = cvtpk(p0, p1);   // p0 low | p1 high
        pk[mf][g][1] = cvtpk(p2, p3);
      }
    }

#pragma unroll
    for (int h = 0; h < 2; ++h) {
      short8 bfr[4];
#pragma unroll
      for (int g = 0; g < 4; ++g) {
        uint4_ bu = {pk[2 * h][g][0], pk[2 * h][g][1], pk[2 * h + 1][g][0], pk[2 * h + 1][g][1]};
        bfr[g] = __builtin_bit_cast(short8, bu);
      }
#pragma unroll
      for (int mf2 = 0; mf2 < 4; ++mf2) {
        int row = mf2 * 16 + lm;
        // permuted-key V A-frag: keys {32h+4q+0..3} and {32h+16+4q+0..3}
        short4_ va = *(const short4_*)&Vtl[row * 64 + ((4 * h + (quad >> 1)) ^ sw) * 8 + (quad & 1) * 4];
        short4_ vb = *(const short4_*)&Vtl[row * 64 + ((4 * h + 2 + (quad >> 1)) ^ sw) * 8 + (quad & 1) * 4];
        short8 af = __builtin_shufflevector(va, vb, 0, 1, 2, 3, 4, 5, 6, 7);
#pragma unroll
        for (int g = 0; g < 4; ++g)
          o[mf2][g] = __builtin_amdgcn_mfma_f32_16x16x32_bf16(af, bfr[g], o[mf2][g], 0, 0, 0);
      }
    }
  }

  // denominator: cross-quad reduce of per-lane partials (once)
  float inv[4];
#pragma unroll
  for (int g = 0; g < 4; ++g) {
    float s = lsum[g];
    s += __shfl_xor(s, 16);
    s += __shfl_xor(s, 32);
    inv[g] = 1.0f / s;
  }

  // epilogue: normalize, swizzled-LDS transpose (reuse staging), coalesced store
  __syncthreads();                       // all waves done with Ks/Vs
  const int b = bh >> 4, h = bh & 15;
  short* epi = &Sh[wave * 4096];         // 64 rows x 64 vd per wave (8 waves)
#pragma unroll
  for (int g = 0; g < 4; ++g) {
#pragma unroll
    for (int mf2 = 0; mf2 < 4; ++mf2) {
      short4_ pkv;
      pkv[0] = f2bf(o[mf2][g][0] * inv[g]); pkv[1] = f2bf(o[mf2][g][1] * inv[g]);
      pkv[2] = f2bf(o[mf2][g][2] * inv[g]); pkv[3] = f2bf(o[mf2][g][3] * inv[g]);
      *(short4_*)&epi[(g * 16 + lm) * 64 + ((2 * mf2 + (quad >> 1)) ^ sw) * 8 + (quad & 1) * 4] = pkv;
    }
  }
  __asm__ volatile("s_waitcnt lgkmcnt(0)" ::: "memory");
#pragma unroll
  for (int pp = 0; pp < 8; ++pp) {
    int lr = pp * 8 + (lane >> 3);
    short8 vv = *(const short8*)&epi[lr * 64 + ((lane & 7) ^ (lr & 7)) * 8];
    *(short8*)&AO[((size_t)(b * Tc + q0 + lr)) * 1024 + h * 64 + (lane & 7) * 8] = vv;
  }
}

// ---------------- launch ----------------
extern "C" void kernel_launch(void* const* d_in, const int* in_sizes, int n_in,
                              void* d_out, int out_size, void* d_ws, size_t ws_size,
                              hipStream_t stream) {
  const float* x  = (const float*)d_in[0];
  const float* Wq = (const float*)d_in[1];
  const float* bq = (const float*)d_in[2];
  const float* Wk = (const float*)d_in[3];
  const float* bk = (const float*)d_in[4];
  const float* Wv = (const float*)d_in[5];
  const float* bv = (const float*)d_in[6];
  const float* Wo = (const float*)d_in[7];
  const float* bo = (const float*)d_in[8];
  float* out = (float*)d_out;

  char* ws = (char*)d_ws;
  size_t off = 0;
  short* xb   = (short*)(ws + off); off += (size_t)MTOT * Dc * 2;
  short* wqkv = (short*)(ws + off); off += (size_t)NQKV * Dc * 2;
  float* bqkv = (float*)(ws + off); off += ((size_t)NQKV * 4 + 255) & ~255ull;
  short* Qb   = (short*)(ws + off); off += (size_t)Bc * Hc * Tc * HDc * 2;
  short* Kb   = (short*)(ws + off); off += (size_t)Bc * Hc * Tc * HDc * 2;
  short* Vt   = (short*)(ws + off); off += (size_t)Bc * Hc * VDc * Tc * 2;
  short* AO   = (short*)(ws + off); off += (size_t)MTOT * 1024 * 2;
  short* wot  = (short*)(ws + off); off += (size_t)Dc * Dc * 2;

  prep_kernel<<<8640, 256, 0, stream>>>(x, xb, Wq, Wk, Wv, bq, bk, bv,
                                        wqkv, bqkv, Wo, wot);
  gemm_qkv_kernel<<<dim3(MTOT / 128, NQKV / 128), 256, 0, stream>>>(xb, wqkv, bqkv, Qb, Kb, Vt);
  attn_kernel<<<dim3(64, 4), 512, 0, stream>>>(Qb, Kb, Vt, AO);
  gemm_out_kernel<<<dim3(MTOT / 128, Dc / 128), 256, 0, stream>>>(AO, wot, bo, out);
}

// Round 12
// 230.270 us; speedup vs baseline: 1.1040x; 1.0149x over previous
//
#include <hip/hip_runtime.h>

// Problem constants
#define Bc 4
#define Tc 2048
#define Dc 1024
#define Hc 16
#define HDc 64
#define VDc 64
#define MTOT (Bc * Tc)      // 8192 rows of x / out
#define NQKV 3072           // Q|K|V stacked output columns

typedef __attribute__((ext_vector_type(8))) short short8;   // 8 x bf16 (4 VGPRs)
typedef __attribute__((ext_vector_type(4))) short short4_;
typedef __attribute__((ext_vector_type(4))) float float4_;
typedef __attribute__((ext_vector_type(4))) unsigned uint4_;

#define QSCALE 0.18033688011112042f   // (1/sqrt(64)) * log2(e), folded into Q

// fp32 -> bf16 (RNE), bit-level
static __device__ __forceinline__ short f2bf(float f) {
  unsigned u = __builtin_bit_cast(unsigned, f);
  u += 0x7fffu + ((u >> 16) & 1u);
  return (short)(u >> 16);
}
// two fp32 -> bf16x2 dword via hardware packed convert (1 VALU op).
// v_cvt_pk_bf16_f32 d,s0,s1: LOW16 = bf16(s0), HIGH16 = bf16(s1).
static __device__ __forceinline__ unsigned cvtpk(float lo, float hi) {
  unsigned r;
  asm("v_cvt_pk_bf16_f32 %0, %1, %2" : "=v"(r) : "v"(lo), "v"(hi));
  return r;
}

// async global->LDS, 16B per lane; l must be wave-uniform (lane*16 implicit)
static __device__ __forceinline__ void gload16(const void* g, void* l) {
  __builtin_amdgcn_global_load_lds(
      (__attribute__((address_space(1))) void*)(unsigned long long)g,
      (__attribute__((address_space(3))) void*)l, 16, 0, 0);
}

// ---------------- fused prep: build_wqkv | build_wo | cvt_x ----------------
// One dispatch. Heavy LDS-transpose blocks FIRST (longest-job-first: they
// have serial __syncthreads phases and would otherwise form the tail):
//   [0, 192)         build_wqkv  (48 x 4 tile grid)
//   [192, 448)       build_wo    (16 x 16 tile grid)
//   [448, 8640)      cvt_x       (8M bf16 elements, 1024/block)
__global__ __launch_bounds__(256) void prep_kernel(
    const float* __restrict__ x, short* __restrict__ xb,
    const float* __restrict__ Wq, const float* __restrict__ Wk,
    const float* __restrict__ Wv, const float* __restrict__ bq,
    const float* __restrict__ bk, const float* __restrict__ bv,
    short* __restrict__ wt, float* __restrict__ bias,
    const float* __restrict__ Wo, short* __restrict__ wot) {
  __shared__ __align__(16) short Lt[64][72];
  const int tid = threadIdx.x;
  const int bid = blockIdx.x;

  if (bid >= 448) {                       // ---- cvt_x ----
    int i = (bid - 448) * 256 + tid;
    float4_ v = reinterpret_cast<const float4_*>(x)[i];
    short4_ o;
    o[0] = f2bf(v[0]); o[1] = f2bf(v[1]); o[2] = f2bf(v[2]); o[3] = f2bf(v[3]);
    reinterpret_cast<short4_*>(xb)[i] = o;
    return;
  }

  if (bid < 192) {                        // ---- build_wqkv ----
    const int idx = bid;
    const int wx = idx % 48, wy = idx / 48;
    const int mat = wx >> 4, h = wx & 15;
    const float* W  = (mat == 0) ? Wq : (mat == 1) ? Wk : Wv;
    const float* bs = (mat == 0) ? bq : (mat == 1) ? bk : bv;
    const int base_n = (mat << 10) + (h << 6);
    if (wy == 0 && tid < 64) bias[base_n + tid] = bs[h * 64 + tid];
    for (int dc = 0; dc < 4; dc++) {
      const int d0 = wy * 256 + dc * 64;
#pragma unroll
      for (int rep = 0; rep < 16; rep++) {
        int dl = rep * 4 + (tid >> 6);
        int hd = tid & 63;
        Lt[hd][dl] = f2bf(W[(size_t)(h * 1024 + d0 + dl) * 64 + hd]);
      }
      __syncthreads();
      int hd = tid >> 2, c = tid & 3;
      short8 v0 = *(const short8*)&Lt[hd][c * 16];
      short8 v1 = *(const short8*)&Lt[hd][c * 16 + 8];
      *(short8*)&wt[(size_t)(base_n + hd) * 1024 + d0 + c * 16] = v0;
      *(short8*)&wt[(size_t)(base_n + hd) * 1024 + d0 + c * 16 + 8] = v1;
      __syncthreads();
    }
    return;
  }

  {                                       // ---- build_wo ----
    const int idx = bid - 192;
    const int n0 = (idx & 15) * 64, k0 = (idx >> 4) * 64;
#pragma unroll
    for (int rep = 0; rep < 16; rep++) {
      int kl = rep * 4 + (tid >> 6);
      int nl = tid & 63;
      Lt[nl][kl] = f2bf(Wo[(size_t)(k0 + kl) * 1024 + n0 + nl]);
    }
    __syncthreads();
    int nl = tid >> 2, c = tid & 3;
    short8 v0 = *(const short8*)&Lt[nl][c * 16];
    short8 v1 = *(const short8*)&Lt[nl][c * 16 + 8];
    *(short8*)&wot[(size_t)(n0 + nl) * 1024 + k0 + c * 16] = v0;
    *(short8*)&wot[(size_t)(n0 + nl) * 1024 + k0 + c * 16 + 8] = v1;
  }
}

// ---------------- double-buffered LDS-staged GEMM K-loop ----------------
#define GEMM_KLOOP(SHSZ)                                                       \
  __shared__ __align__(16) short Sh[SHSZ];                                     \
  const int tid = threadIdx.x;                                                 \
  const int wave = tid >> 6, lane = tid & 63;                                  \
  const int lm = lane & 15, quad = lane >> 4;                                  \
  const int wm = (wave & 1) * 64, wn = (wave >> 1) * 64;                       \
  const int srow = tid >> 2, pchunk = tid & 3;                                 \
  const int swr = (srow ^ (srow >> 2)) & 3;                                    \
  const int pq = quad ^ ((lm ^ (lm >> 2)) & 3);                                \
  const short* Ag = A + (size_t)(m0 + srow) * 1024 + (pchunk ^ swr) * 8;       \
  const short* Bg = Bt + (size_t)(n0 + srow) * 1024 + (pchunk ^ swr) * 8;      \
  float4_ acc[4][4] = {};                                                      \
  gload16(Ag, &Sh[wave * 512]);                                                \
  gload16(Ag + 64 * 1024, &Sh[2048 + wave * 512]);                             \
  gload16(Bg, &Sh[4096 + wave * 512]);                                         \
  gload16(Bg + 64 * 1024, &Sh[6144 + wave * 512]);                             \
  for (int k0 = 0; k0 < 1024; k0 += 32) {                                      \
    const int cb = (k0 >> 5) & 1;                                              \
    __syncthreads();                                                           \
    if (k0 + 32 < 1024) {                                                      \
      short* d = &Sh[(1 - cb) * 8192];                                         \
      gload16(Ag + k0 + 32, d + wave * 512);                                   \
      gload16(Ag + 64 * 1024 + k0 + 32, d + 2048 + wave * 512);                \
      gload16(Bg + k0 + 32, d + 4096 + wave * 512);                            \
      gload16(Bg + 64 * 1024 + k0 + 32, d + 6144 + wave * 512);                \
    }                                                                          \
    const short* Ab = &Sh[cb * 8192];                                          \
    const short* Bb = &Sh[cb * 8192 + 4096];                                   \
    short8 af[4], bf[4];                                                       \
    _Pragma("unroll") for (int i = 0; i < 4; i++) {                            \
      af[i] = *(const short8*)&Ab[(wm + i * 16 + lm) * 32 + pq * 8];           \
      bf[i] = *(const short8*)&Bb[(wn + i * 16 + lm) * 32 + pq * 8];           \
    }                                                                          \
    _Pragma("unroll") for (int i = 0; i < 4; i++)                              \
      _Pragma("unroll") for (int j = 0; j < 4; j++)                            \
        acc[i][j] = __builtin_amdgcn_mfma_f32_16x16x32_bf16(af[i], bf[j],      \
                                                            acc[i][j], 0, 0, 0); \
  }

// QKV projection: A = xb [8192][1024], Bt = wqkv [3072][1024].
// Default block mapping is already XCD-optimal: grid (64 m, 24 n) with
// 64 % 8 == 0 gives XCD = m mod 8 -> each XCD keeps 8 A-panels (2 MB)
// L2-resident, reused across all 24 n-panels. Do NOT swizzle (R10: 4x FETCH).
__global__ __launch_bounds__(256) void gemm_qkv_kernel(
    const short* __restrict__ A, const short* __restrict__ Bt,
    const float* __restrict__ bias,
    short* __restrict__ Qb, short* __restrict__ Kb, short* __restrict__ Vt) {
  const int m0 = blockIdx.x * 128, n0 = blockIdx.y * 128;
  GEMM_KLOOP(18432)
  __syncthreads();                       // all waves done reading Sh
  short* epi = &Sh[wave * 4608];         // 64 x 72 shorts per wave
  const int mat = n0 >> 10;
  const int hh = ((n0 + wn) >> 6) & 15;
  const int b = m0 >> 11;
  const int bh = b * Hc + hh;
  const int t0 = (m0 & (Tc - 1)) + wm;
  if (mat < 2) {                         // Q/K: epi[t][hd]
    const float sc = (mat == 0) ? QSCALE : 1.0f;
#pragma unroll
    for (int j = 0; j < 4; j++) {
      float bvs = bias[n0 + wn + j * 16 + lm] * sc;
#pragma unroll
      for (int i = 0; i < 4; i++)
#pragma unroll
        for (int r = 0; r < 4; r++)
          epi[(i * 16 + quad * 4 + r) * 72 + j * 16 + lm] = f2bf(acc[i][j][r] * sc + bvs);
    }
    __asm__ volatile("s_waitcnt lgkmcnt(0)" ::: "memory");
    short* dst = (mat == 0) ? Qb : Kb;
#pragma unroll
    for (int p = 0; p < 8; p++) {
      int lrow = p * 8 + (lane >> 3);
      short8 v = *(const short8*)&epi[lrow * 72 + (lane & 7) * 8];
      *(short8*)&dst[((size_t)bh * Tc + t0 + lrow) * HDc + (lane & 7) * 8] = v;
    }
  } else {                               // V: epi[hd][t] (transposed, b64 packs)
#pragma unroll
    for (int j = 0; j < 4; j++) {
      float bv = bias[n0 + wn + j * 16 + lm];
#pragma unroll
      for (int i = 0; i < 4; i++) {
        short4_ pk;
#pragma unroll
        for (int r = 0; r < 4; r++) pk[r] = f2bf(acc[i][j][r] + bv);
        *(short4_*)&epi[(j * 16 + lm) * 72 + i * 16 + quad * 4] = pk;
      }
    }
    __asm__ volatile("s_waitcnt lgkmcnt(0)" ::: "memory");
#pragma unroll
    for (int p = 0; p < 8; p++) {
      int hdrow = p * 8 + (lane >> 3);
      short8 v = *(const short8*)&epi[hdrow * 72 + (lane & 7) * 8];
      *(short8*)&Vt[((size_t)bh * VDc + hdrow) * Tc + t0 + (lane & 7) * 8] = v;
    }
  }
}

// Output projection: A = AO [8192][1024], Bt = wot [1024][1024], fp32 out.
__global__ __launch_bounds__(256) void gemm_out_kernel(
    const short* __restrict__ A, const short* __restrict__ Bt,
    const float* __restrict__ bo, float* __restrict__ out) {
  const int m0 = blockIdx.x * 128, n0 = blockIdx.y * 128;
  GEMM_KLOOP(16384)
#pragma unroll
  for (int j = 0; j < 4; j++) {
    int n = n0 + wn + j * 16 + lm;
    float bv = bo[n];
#pragma unroll
    for (int i = 0; i < 4; i++) {
#pragma unroll
      for (int r = 0; r < 4; r++) {
        int m = m0 + wm + i * 16 + quad * 4 + r;
        out[(size_t)m * Dc + n] = acc[i][j][r] + bv;
      }
    }
  }
}

// ---------------- flash attention (causal), transposed scores ----------------
// 16-wave variant of the R9/R11 pair-block skeleton (latency-hiding upgrade):
// one 1024-thread block per (bh, pair p). Waves 0-7 own qblk 7-p with 32
// q-rows each (wave w covers rows (7-p)*256 + (w&7)*32); waves 8-15 own
// qblk p likewise. Per-wave MFMA group count halves (g<2), wave count
// doubles -> 4 waves/SIMD interleave the dependency chains that left
// VALUBusy at ~30% with 2 waves/SIMD. Shared-prefix staging as R9: ONE
// K/V stream serves both qblks; K staged by waves 0-7, V by waves 8-15
// (identical formulas via t9 = tid & 511). Tile layout, chunk-XOR swizzle,
// double-buffer bases, PV permuted addressing, __syncthreads skeleton are
// byte-identical to R9. LDS 64 KiB (epilogue: 16 waves x 2048 shorts).
__global__ __launch_bounds__(1024) void attn_kernel(
    const short* __restrict__ Qb, const short* __restrict__ Kb,
    const short* __restrict__ Vt, short* __restrict__ AO) {
  __shared__ __align__(16) short Sh[32768];
  const int tid = threadIdx.x;
  const int wave = tid >> 6, lane = tid & 63;
  const int lm = lane & 15, quad = lane >> 4;
  const int bh = blockIdx.x;
  const int p = blockIdx.y;                   // pair index 0..3
  const int qblk = (wave < 8) ? (7 - p) : p;
  const int q0 = qblk * 256 + (wave & 7) * 32;   // 32 rows per wave
  const int nt = 4 * (7 - p) + 4;             // loop bound = large member's

  const short* Qp = Qb + (size_t)bh * Tc * HDc;
  const short* Kp = Kb + (size_t)bh * Tc * HDc;
  const short* Vp = Vt + (size_t)bh * VDc * Tc;

  const int t9 = tid & 511;
  const int srow = t9 >> 3;                  // 0..63
  const int chlog = (t9 & 7) ^ (srow & 7);
  const int sw = lm & 7;
  const bool stK = (tid < 512);              // waves 0-7 stage K, 8-15 stage V
  const int w8 = wave & 7;

  short8 qf[2][2];
#pragma unroll
  for (int g = 0; g < 2; g++)
#pragma unroll
    for (int h = 0; h < 2; h++)
      qf[g][h] = *(const short8*)&Qp[(q0 + g * 16 + lm) * HDc + h * 32 + quad * 8];

  float4_ o[4][2] = {};        // Oᵀ[vd=16mf2+4quad+r][qrow=16g+lm]
  float lsum[2] = {};
  unsigned pk[4][2][2];        // pk[mf][g]: keys {16mf+4q+0..3} as bf16x2 pairs

  // prologue: tile 0 (each thread: 1 gload; K by waves 0-7, V by 8-15)
  if (stK) gload16(Kp + (size_t)srow * HDc + chlog * 8, &Sh[w8 * 512]);
  else     gload16(Vp + (size_t)srow * Tc + chlog * 8, &Sh[8192 + w8 * 512]);

  for (int it = 0; it < nt; ++it) {
    const int kt = it << 6;
    const int cur = it & 1;
    __syncthreads();                    // tile `it` staged
    if (it + 1 < nt) {
      const int ktn = kt + 64;
      const int nb = (1 - cur) * 4096;
      if (stK) gload16(Kp + (size_t)(ktn + srow) * HDc + chlog * 8, &Sh[nb + w8 * 512]);
      else     gload16(Vp + (size_t)srow * Tc + ktn + chlog * 8, &Sh[8192 + nb + w8 * 512]);
    }
    if (kt > q0 + 31) continue;         // fully-masked tile (wave-uniform)
    const short* Kt = &Sh[cur * 4096];
    const short* Vtl = &Sh[8192 + cur * 4096];
    const bool diag = (kt + 63 > q0);

#pragma unroll
    for (int mf = 0; mf < 4; ++mf) {
      int row = mf * 16 + lm;
      short8 k0 = *(const short8*)&Kt[row * 64 + (quad ^ sw) * 8];
      short8 k1 = *(const short8*)&Kt[row * 64 + ((4 + quad) ^ sw) * 8];
      float4_ st[2];
#pragma unroll
      for (int g = 0; g < 2; ++g) {
        float4_ s = {};
        s = __builtin_amdgcn_mfma_f32_16x16x32_bf16(k0, qf[g][0], s, 0, 0, 0);
        s = __builtin_amdgcn_mfma_f32_16x16x32_bf16(k1, qf[g][1], s, 0, 0, 0);
        st[g] = s;
      }
      if (diag) {
#pragma unroll
        for (int g = 0; g < 2; ++g) {
          int qrow = q0 + g * 16 + lm;
#pragma unroll
          for (int r = 0; r < 4; ++r)
            if (kt + mf * 16 + quad * 4 + r > qrow) st[g][r] = -1e30f;
        }
      }
#pragma unroll
      for (int g = 0; g < 2; ++g) {
        float p0 = __builtin_amdgcn_exp2f(st[g][0]);
        float p1 = __builtin_amdgcn_exp2f(st[g][1]);
        float p2 = __builtin_amdgcn_exp2f(st[g][2]);
        float p3 = __builtin_amdgcn_exp2f(st[g][3]);
        lsum[g] += (p0 + p1) + (p2 + p3);
        pk[mf][g][0] = cvtpk(p0, p1);   // p0 low | p1 high
        pk[mf][g][1] = cvtpk(p2, p3);
      }
    }

#pragma unroll
    for (int h = 0; h < 2; ++h) {
      short8 bfr[2];
#pragma unroll
      for (int g = 0; g < 2; ++g) {
        uint4_ bu = {pk[2 * h][g][0], pk[2 * h][g][1], pk[2 * h + 1][g][0], pk[2 * h + 1][g][1]};
        bfr[g] = __builtin_bit_cast(short8, bu);
      }
#pragma unroll
      for (int mf2 = 0; mf2 < 4; ++mf2) {
        int row = mf2 * 16 + lm;
        // permuted-key V A-frag: keys {32h+4q+0..3} and {32h+16+4q+0..3}
        short4_ va = *(const short4_*)&Vtl[row * 64 + ((4 * h + (quad >> 1)) ^ sw) * 8 + (quad & 1) * 4];
        short4_ vb = *(const short4_*)&Vtl[row * 64 + ((4 * h + 2 + (quad >> 1)) ^ sw) * 8 + (quad & 1) * 4];
        short8 af = __builtin_shufflevector(va, vb, 0, 1, 2, 3, 4, 5, 6, 7);
#pragma unroll
        for (int g = 0; g < 2; ++g)
          o[mf2][g] = __builtin_amdgcn_mfma_f32_16x16x32_bf16(af, bfr[g], o[mf2][g], 0, 0, 0);
      }
    }
  }

  // denominator: cross-quad reduce of per-lane partials (once)
  float inv[2];
#pragma unroll
  for (int g = 0; g < 2; ++g) {
    float s = lsum[g];
    s += __shfl_xor(s, 16);
    s += __shfl_xor(s, 32);
    inv[g] = 1.0f / s;
  }

  // epilogue: normalize, swizzled-LDS transpose (reuse staging), coalesced store
  __syncthreads();                       // all waves done with Ks/Vs
  const int b = bh >> 4, h = bh & 15;
  short* epi = &Sh[wave * 2048];         // 32 rows x 64 vd per wave (16 waves)
#pragma unroll
  for (int g = 0; g < 2; ++g) {
#pragma unroll
    for (int mf2 = 0; mf2 < 4; ++mf2) {
      short4_ pkv;
      pkv[0] = f2bf(o[mf2][g][0] * inv[g]); pkv[1] = f2bf(o[mf2][g][1] * inv[g]);
      pkv[2] = f2bf(o[mf2][g][2] * inv[g]); pkv[3] = f2bf(o[mf2][g][3] * inv[g]);
      *(short4_*)&epi[(g * 16 + lm) * 64 + ((2 * mf2 + (quad >> 1)) ^ sw) * 8 + (quad & 1) * 4] = pkv;
    }
  }
  __asm__ volatile("s_waitcnt lgkmcnt(0)" ::: "memory");
#pragma unroll
  for (int pp = 0; pp < 4; ++pp) {
    int lr = pp * 8 + (lane >> 3);       // 0..31
    short8 vv = *(const short8*)&epi[lr * 64 + ((lane & 7) ^ (lr & 7)) * 8];
    *(short8*)&AO[((size_t)(b * Tc + q0 + lr)) * 1024 + h * 64 + (lane & 7) * 8] = vv;
  }
}

// ---------------- launch ----------------
extern "C" void kernel_launch(void* const* d_in, const int* in_sizes, int n_in,
                              void* d_out, int out_size, void* d_ws, size_t ws_size,
                              hipStream_t stream) {
  const float* x  = (const float*)d_in[0];
  const float* Wq = (const float*)d_in[1];
  const float* bq = (const float*)d_in[2];
  const float* Wk = (const float*)d_in[3];
  const float* bk = (const float*)d_in[4];
  const float* Wv = (const float*)d_in[5];
  const float* bv = (const float*)d_in[6];
  const float* Wo = (const float*)d_in[7];
  const float* bo = (const float*)d_in[8];
  float* out = (float*)d_out;

  char* ws = (char*)d_ws;
  size_t off = 0;
  short* xb   = (short*)(ws + off); off += (size_t)MTOT * Dc * 2;
  short* wqkv = (short*)(ws + off); off += (size_t)NQKV * Dc * 2;
  float* bqkv = (float*)(ws + off); off += ((size_t)NQKV * 4 + 255) & ~255ull;
  short* Qb   = (short*)(ws + off); off += (size_t)Bc * Hc * Tc * HDc * 2;
  short* Kb   = (short*)(ws + off); off += (size_t)Bc * Hc * Tc * HDc * 2;
  short* Vt   = (short*)(ws + off); off += (size_t)Bc * Hc * VDc * Tc * 2;
  short* AO   = (short*)(ws + off); off += (size_t)MTOT * 1024 * 2;
  short* wot  = (short*)(ws + off); off += (size_t)Dc * Dc * 2;

  prep_kernel<<<8640, 256, 0, stream>>>(x, xb, Wq, Wk, Wv, bq, bk, bv,
                                        wqkv, bqkv, Wo, wot);
  gemm_qkv_kernel<<<dim3(MTOT / 128, NQKV / 128), 256, 0, stream>>>(xb, wqkv, bqkv, Qb, Kb, Vt);
  attn_kernel<<<dim3(64, 4), 1024, 0, stream>>>(Qb, Kb, Vt, AO);
  gemm_out_kernel<<<dim3(MTOT / 128, Dc / 128), 256, 0, stream>>>(AO, wot, bo, out);
}